// Round 9
// baseline (162.042 us; speedup 1.0000x reference)
//
#include <hip/hip_runtime.h>

#define DD 256
#define BB 8
#define NA 360

typedef _Float16 half2_t __attribute__((ext_vector_type(2)));

#if defined(__has_builtin)
#if __has_builtin(__builtin_elementwise_fma)
#define PKFMA(a, b, c) __builtin_elementwise_fma((a), (b), (c))
#endif
#endif
#ifndef PKFMA
#define PKFMA(a, b, c) ((a) * (b) + (c))
#endif

__device__ __forceinline__ half2_t h2(unsigned u) {
    return __builtin_bit_cast(half2_t, u);
}
__device__ __forceinline__ half2_t bcast2(float w) {   // v_cvt_pkrtz (w,w)
    return __builtin_bit_cast(half2_t, __builtin_amdgcn_cvt_pkrtz(w, w));
}
__device__ __forceinline__ unsigned pk_f16(float a, float b) {
    unsigned short ua = __builtin_bit_cast(unsigned short, (_Float16)a);
    unsigned short ub = __builtin_bit_cast(unsigned short, (_Float16)b);
    return (unsigned)ua | ((unsigned)ub << 16);
}

// ---- fused: pack (blocks 0..255) -> sw grid barrier -> radon gather -------
// ws: [0,1MB) pN f16x8/pixel row-major; [1MB,2MB) pT transposed; [2MB] counter
__global__ __launch_bounds__(256) void radon_fused(const float* __restrict__ x,
                                                   uint4* __restrict__ pN,
                                                   uint4* __restrict__ pT,
                                                   unsigned* __restrict__ cnt,
                                                   float* __restrict__ out) {
    __shared__ uint4 tile[16][17];           // pack transpose staging (4.3 KB)
    __shared__ float part[4][64][BB];        // radon reduction (8 KB)

    const int bx  = blockIdx.x;              // 0..1439
    const int tid = threadIdx.x;

    // ---------------- phase 1: pack (first 256 blocks) ----------------
    if (bx < 256) {
        const int tx = tid & 15, ty = tid >> 4;
        const int px0 = (bx & 15) * 16, py0 = (bx >> 4) * 16;
        const int pix = (py0 + ty) * DD + px0 + tx;
        uint4 v;
        v.x = pk_f16(x[0 * DD * DD + pix], x[1 * DD * DD + pix]);
        v.y = pk_f16(x[2 * DD * DD + pix], x[3 * DD * DD + pix]);
        v.z = pk_f16(x[4 * DD * DD + pix], x[5 * DD * DD + pix]);
        v.w = pk_f16(x[6 * DD * DD + pix], x[7 * DD * DD + pix]);
        pN[pix] = v;                         // coalesced
        tile[ty][tx] = v;
        __syncthreads();
        // pT[xx*D+yy] = img[yy][xx], coalesced store
        pT[(px0 + ty) * DD + py0 + tx] = tile[tx][ty];
        // __syncthreads drains vmcnt for the whole block before the barrier,
        // so all pack stores are at least in L2 when thread 0 signals.
        __syncthreads();
        if (tid == 0)
            __hip_atomic_fetch_add(cnt, 1u, __ATOMIC_RELEASE, __HIP_MEMORY_SCOPE_AGENT);
    }

    // ---------------- grid barrier: wait for 256 pack signals ----------
    if (tid == 0) {
        while (__hip_atomic_load(cnt, __ATOMIC_RELAXED, __HIP_MEMORY_SCOPE_AGENT) < 256u)
            __builtin_amdgcn_s_sleep(4);
        __atomic_thread_fence(__ATOMIC_ACQUIRE);   // one buffer_inv, not per spin
    }
    __syncthreads();

    // ---------------- phase 2: radon (all 1440 blocks) -----------------
    const int a    = bx >> 2;                // angle
    const int wseg = bx & 3;                 // 0..3
    const int g    = tid >> 6;               // wave = h-phase 0..3
    const int lane = tid & 63;
    const int w    = wseg * 64 + lane;

    const float ang = (float)a * 0.5f;
    const float t = ang * 0.017453292519943295f;
    const float s = sinf(t);
    const float c = cosf(t);

    const float uw  = (float)w - 127.5f;
    const float axN = fmaf(c, uw, 127.5f);
    const float ayN = fmaf(s, uw, 127.5f);

    const uint4* __restrict__ P;
    float ax, dx, ay, dy;                    // inner = ax+dx*uh, row = ay+dy*uh
    if (fabsf(s) <= fabsf(c)) { P = pN; ax = axN; dx = -s; ay = ayN; dy = c;  }
    else                      { P = pT; ax = ayN; dx = c;  ay = axN; dy = -s; }

    half2_t acc2[4];
#pragma unroll
    for (int j = 0; j < 4; ++j) acc2[j] = half2_t{(_Float16)0, (_Float16)0};

#pragma unroll 4
    for (int i = 0; i < 64; ++i) {
        const float uh = (float)(g + 4 * i) - 127.5f;
        const float ix = fmaf(dx, uh, ax);
        const float iy = fmaf(dy, uh, ay);
        const float x0f = floorf(ix), y0f = floorf(iy);
        const float wx1 = ix - x0f, wy1 = iy - y0f;
        const float wx0 = 1.f - wx1, wy0 = 1.f - wy1;
        const int x0 = (int)x0f, y0 = (int)y0f;
        const float vx0 = ((unsigned)x0 < 256u) ? wx0 : 0.f;
        const float vx1 = ((unsigned)(x0 + 1) < 256u) ? wx1 : 0.f;
        const float vy0 = ((unsigned)y0 < 256u) ? wy0 : 0.f;
        const float vy1 = ((unsigned)(y0 + 1) < 256u) ? wy1 : 0.f;
        const int x0c = min(max(x0, 0), 255);
        const int x1c = min(max(x0 + 1, 0), 255);
        const int y0c = min(max(y0, 0), 255);
        const int y1c = min(max(y0 + 1, 0), 255);

        const uint4 q00 = P[y0c * DD + x0c];
        const uint4 q10 = P[y0c * DD + x1c];
        const uint4 q01 = P[y1c * DD + x0c];
        const uint4 q11 = P[y1c * DD + x1c];

        const half2_t w00 = bcast2(vx0 * vy0);
        const half2_t w10 = bcast2(vx1 * vy0);
        const half2_t w01 = bcast2(vx0 * vy1);
        const half2_t w11 = bcast2(vx1 * vy1);

        acc2[0] = PKFMA(h2(q00.x), w00, acc2[0]);
        acc2[1] = PKFMA(h2(q00.y), w00, acc2[1]);
        acc2[2] = PKFMA(h2(q00.z), w00, acc2[2]);
        acc2[3] = PKFMA(h2(q00.w), w00, acc2[3]);
        acc2[0] = PKFMA(h2(q10.x), w10, acc2[0]);
        acc2[1] = PKFMA(h2(q10.y), w10, acc2[1]);
        acc2[2] = PKFMA(h2(q10.z), w10, acc2[2]);
        acc2[3] = PKFMA(h2(q10.w), w10, acc2[3]);
        acc2[0] = PKFMA(h2(q01.x), w01, acc2[0]);
        acc2[1] = PKFMA(h2(q01.y), w01, acc2[1]);
        acc2[2] = PKFMA(h2(q01.z), w01, acc2[2]);
        acc2[3] = PKFMA(h2(q01.w), w01, acc2[3]);
        acc2[0] = PKFMA(h2(q11.x), w11, acc2[0]);
        acc2[1] = PKFMA(h2(q11.y), w11, acc2[1]);
        acc2[2] = PKFMA(h2(q11.z), w11, acc2[2]);
        acc2[3] = PKFMA(h2(q11.w), w11, acc2[3]);
    }

    float acc[BB];
#pragma unroll
    for (int j = 0; j < 4; ++j) {
        acc[2 * j]     = (float)acc2[j].x;
        acc[2 * j + 1] = (float)acc2[j].y;
    }

#pragma unroll
    for (int b = 0; b < BB; b += 4)
        *(float4*)&part[g][lane][b] = make_float4(acc[b], acc[b + 1], acc[b + 2], acc[b + 3]);
    __syncthreads();

    const float sc = 1.0f / 256.0f;
#pragma unroll
    for (int k = 0; k < 2; ++k) {
        const int id = tid + k * 256;        // (b, wl)
        const int b  = id >> 6;
        const int wl = id & 63;
        const float v = part[0][wl][b] + part[1][wl][b] + part[2][wl][b] + part[3][wl][b];
        out[(size_t)b * NA * DD + (size_t)a * DD + wseg * 64 + wl] = v * sc;
    }
}

// ---- fallback (ws too small): direct fp32 gather with atomics -------------
__global__ __launch_bounds__(256) void radon_direct(const float* __restrict__ x,
                                                    float* __restrict__ out) {
    const int a  = blockIdx.x;
    const int hc = blockIdx.y;
    const int w  = threadIdx.x;
    const float ang = (float)a * 0.5f;
    const float t = ang * 0.017453292519943295f;
    const float s = sinf(t);
    const float c = cosf(t);
    const float uw = (float)w - 127.5f;
    const float ax = fmaf(c, uw, 127.5f);
    const float ay = fmaf(s, uw, 127.5f);

    float acc[BB];
#pragma unroll
    for (int b = 0; b < BB; ++b) acc[b] = 0.f;

    const int h0 = hc * 32;
    for (int i = 0; i < 32; ++i) {
        const float uh = (float)(h0 + i) - 127.5f;
        const float ix = fmaf(-s, uh, ax);
        const float iy = fmaf(c, uh, ay);
        const float x0f = floorf(ix), y0f = floorf(iy);
        const float wx1 = ix - x0f, wy1 = iy - y0f;
        const float wx0 = 1.f - wx1, wy0 = 1.f - wy1;
        const int x0 = (int)x0f, y0 = (int)y0f;
        const float vx0 = ((unsigned)x0 < 256u) ? wx0 : 0.f;
        const float vx1 = ((unsigned)(x0 + 1) < 256u) ? wx1 : 0.f;
        const float vy0 = ((unsigned)y0 < 256u) ? wy0 : 0.f;
        const float vy1 = ((unsigned)(y0 + 1) < 256u) ? wy1 : 0.f;
        const int x0c = min(max(x0, 0), 255);
        const int x1c = min(max(x0 + 1, 0), 255);
        const int y0c = min(max(y0, 0), 255);
        const int y1c = min(max(y0 + 1, 0), 255);
        const float w00 = vx0 * vy0, w10 = vx1 * vy0;
        const float w01 = vx0 * vy1, w11 = vx1 * vy1;
        const int l00 = y0c * DD + x0c, l10 = y0c * DD + x1c;
        const int l01 = y1c * DD + x0c, l11 = y1c * DD + x1c;
#pragma unroll
        for (int b = 0; b < BB; ++b) {
            const float* ib = x + (size_t)b * DD * DD;
            acc[b] = fmaf(ib[l00], w00, acc[b]);
            acc[b] = fmaf(ib[l10], w10, acc[b]);
            acc[b] = fmaf(ib[l01], w01, acc[b]);
            acc[b] = fmaf(ib[l11], w11, acc[b]);
        }
    }

    const float sc = 1.0f / 256.0f;
    float* o = out + (size_t)a * DD + w;
#pragma unroll
    for (int b = 0; b < BB; ++b)
        atomicAdd(o + (size_t)b * NA * DD, acc[b] * sc);
}

extern "C" void kernel_launch(void* const* d_in, const int* in_sizes, int n_in,
                              void* d_out, int out_size, void* d_ws, size_t ws_size,
                              hipStream_t stream) {
    const float* x = (const float*)d_in[0];
    float* out = (float*)d_out;

    const size_t need = (2ull << 20) + 64;   // pN + pT + counter
    if (ws_size >= need) {
        uint4* pN = (uint4*)d_ws;
        uint4* pT = pN + (size_t)DD * DD;
        unsigned* cnt = (unsigned*)((char*)d_ws + (2ull << 20));
        // ws is poisoned 0xAA each call -> deterministically zero the counter
        (void)hipMemsetAsync(cnt, 0, sizeof(unsigned), stream);
        radon_fused<<<NA * 4, 256, 0, stream>>>(x, pN, pT, cnt, out);
    } else {
        (void)hipMemsetAsync(d_out, 0, (size_t)out_size * sizeof(float), stream);
        radon_direct<<<dim3(NA, 8), 256, 0, stream>>>(x, out);
    }
}

// Round 10
// 124.964 us; speedup vs baseline: 1.2967x; 1.2967x over previous
//
#include <hip/hip_runtime.h>

#define DD 256
#define BB 8
#define NA 360

typedef _Float16 half2_t __attribute__((ext_vector_type(2)));

#if defined(__has_builtin)
#if __has_builtin(__builtin_elementwise_fma)
#define PKFMA(a, b, c) __builtin_elementwise_fma((a), (b), (c))
#endif
#endif
#ifndef PKFMA
#define PKFMA(a, b, c) ((a) * (b) + (c))
#endif

__device__ __forceinline__ half2_t h2(unsigned u) {
    return __builtin_bit_cast(half2_t, u);
}
__device__ __forceinline__ half2_t bcast2(float w) {   // v_cvt_pkrtz (w,w)
    return __builtin_bit_cast(half2_t, __builtin_amdgcn_cvt_pkrtz(w, w));
}
__device__ __forceinline__ unsigned pk_f16(float a, float b) {
    unsigned short ua = __builtin_bit_cast(unsigned short, (_Float16)a);
    unsigned short ub = __builtin_bit_cast(unsigned short, (_Float16)b);
    return (unsigned)ua | ((unsigned)ub << 16);
}

// ---- pack: (B,1,D,D) fp32 -> f16x8/pixel pN + transposed pT ---------------
// 256 blocks (16x16 tiles) so pack saturates all 256 CUs (~1.5us).
__global__ __launch_bounds__(256) void pack_f16(const float* __restrict__ x,
                                                uint4* __restrict__ pN,
                                                uint4* __restrict__ pT) {
    __shared__ uint4 t[16][17];
    const int tx = threadIdx.x & 15;
    const int ty = threadIdx.x >> 4;              // 0..15
    const int x0 = (blockIdx.x & 15) * 16;
    const int y0 = (blockIdx.x >> 4) * 16;

    const int pix = (y0 + ty) * DD + x0 + tx;
    uint4 v;
    v.x = pk_f16(x[0 * DD * DD + pix], x[1 * DD * DD + pix]);
    v.y = pk_f16(x[2 * DD * DD + pix], x[3 * DD * DD + pix]);
    v.z = pk_f16(x[4 * DD * DD + pix], x[5 * DD * DD + pix]);
    v.w = pk_f16(x[6 * DD * DD + pix], x[7 * DD * DD + pix]);
    pN[pix] = v;                                   // coalesced
    t[ty][tx] = v;
    __syncthreads();
    // pT[xx*D+yy] = img[yy][xx]
    pT[(x0 + ty) * DD + y0 + tx] = t[tx][ty];      // coalesced
}

// ---- radon (R7 structure — at the scattered-load addr-processing floor) ---
// block = (angle, w-quarter); 4 waves = interleaved h-phases; LDS reduce;
// exclusive coalesced stores (no atomics, no output memset needed).
// Per h-step: 4 scattered b128 loads (the 32-cyc/load TA floor) + 16 pk_fma.
__global__ __launch_bounds__(256) void radon_pk(const uint4* __restrict__ pN,
                                                const uint4* __restrict__ pT,
                                                float* __restrict__ out) {
    const int a    = blockIdx.x;            // angle
    const int wseg = blockIdx.y;            // 0..3
    const int g    = threadIdx.x >> 6;      // wave = h-phase 0..3
    const int lane = threadIdx.x & 63;
    const int w    = wseg * 64 + lane;

    const float ang = (float)a * 0.5f;
    const float t = ang * 0.017453292519943295f;
    const float s = sinf(t);
    const float c = cosf(t);

    const float uw  = (float)w - 127.5f;
    const float axN = fmaf(c, uw, 127.5f);
    const float ayN = fmaf(s, uw, 127.5f);

    // inner coord = contiguous dim of chosen layout (h-step = min(|s|,|c|))
    const uint4* __restrict__ P;
    float ax, dx, ay, dy;                    // inner = ax+dx*uh, row = ay+dy*uh
    if (fabsf(s) <= fabsf(c)) { P = pN; ax = axN; dx = -s; ay = ayN; dy = c;  }
    else                      { P = pT; ax = ayN; dx = c;  ay = axN; dy = -s; }

    half2_t acc2[4];
#pragma unroll
    for (int j = 0; j < 4; ++j) acc2[j] = half2_t{(_Float16)0, (_Float16)0};

    // h = g + 4*i : the block's 4 waves march through adjacent h together
#pragma unroll 4
    for (int i = 0; i < 64; ++i) {
        const float uh = (float)(g + 4 * i) - 127.5f;
        const float ix = fmaf(dx, uh, ax);
        const float iy = fmaf(dy, uh, ay);
        const float x0f = floorf(ix), y0f = floorf(iy);
        const float wx1 = ix - x0f, wy1 = iy - y0f;
        const float wx0 = 1.f - wx1, wy0 = 1.f - wy1;
        const int x0 = (int)x0f, y0 = (int)y0f;
        const float vx0 = ((unsigned)x0 < 256u) ? wx0 : 0.f;
        const float vx1 = ((unsigned)(x0 + 1) < 256u) ? wx1 : 0.f;
        const float vy0 = ((unsigned)y0 < 256u) ? wy0 : 0.f;
        const float vy1 = ((unsigned)(y0 + 1) < 256u) ? wy1 : 0.f;
        const int x0c = min(max(x0, 0), 255);
        const int x1c = min(max(x0 + 1, 0), 255);
        const int y0c = min(max(y0, 0), 255);
        const int y1c = min(max(y0 + 1, 0), 255);

        const uint4 q00 = P[y0c * DD + x0c];
        const uint4 q10 = P[y0c * DD + x1c];
        const uint4 q01 = P[y1c * DD + x0c];
        const uint4 q11 = P[y1c * DD + x1c];

        const half2_t w00 = bcast2(vx0 * vy0);
        const half2_t w10 = bcast2(vx1 * vy0);
        const half2_t w01 = bcast2(vx0 * vy1);
        const half2_t w11 = bcast2(vx1 * vy1);

        acc2[0] = PKFMA(h2(q00.x), w00, acc2[0]);
        acc2[1] = PKFMA(h2(q00.y), w00, acc2[1]);
        acc2[2] = PKFMA(h2(q00.z), w00, acc2[2]);
        acc2[3] = PKFMA(h2(q00.w), w00, acc2[3]);
        acc2[0] = PKFMA(h2(q10.x), w10, acc2[0]);
        acc2[1] = PKFMA(h2(q10.y), w10, acc2[1]);
        acc2[2] = PKFMA(h2(q10.z), w10, acc2[2]);
        acc2[3] = PKFMA(h2(q10.w), w10, acc2[3]);
        acc2[0] = PKFMA(h2(q01.x), w01, acc2[0]);
        acc2[1] = PKFMA(h2(q01.y), w01, acc2[1]);
        acc2[2] = PKFMA(h2(q01.z), w01, acc2[2]);
        acc2[3] = PKFMA(h2(q01.w), w01, acc2[3]);
        acc2[0] = PKFMA(h2(q11.x), w11, acc2[0]);
        acc2[1] = PKFMA(h2(q11.y), w11, acc2[1]);
        acc2[2] = PKFMA(h2(q11.z), w11, acc2[2]);
        acc2[3] = PKFMA(h2(q11.w), w11, acc2[3]);
    }

    // ---- widen to f32, in-block reduction over 4 h-phases, exclusive store
    float acc[BB];
#pragma unroll
    for (int j = 0; j < 4; ++j) {
        acc[2 * j]     = (float)acc2[j].x;
        acc[2 * j + 1] = (float)acc2[j].y;
    }

    __shared__ float part[4][64][BB];        // 8 KB
#pragma unroll
    for (int b = 0; b < BB; b += 4)
        *(float4*)&part[g][lane][b] = make_float4(acc[b], acc[b + 1], acc[b + 2], acc[b + 3]);
    __syncthreads();

    const float sc = 1.0f / 256.0f;
#pragma unroll
    for (int k = 0; k < 2; ++k) {
        const int id = threadIdx.x + k * 256;  // 0..511 -> (b, wl)
        const int b  = id >> 6;
        const int wl = id & 63;
        const float v = part[0][wl][b] + part[1][wl][b] + part[2][wl][b] + part[3][wl][b];
        out[(size_t)b * NA * DD + (size_t)a * DD + wseg * 64 + wl] = v * sc;
    }
}

// ---- fallback (ws too small): direct fp32 gather with atomics -------------
__global__ __launch_bounds__(256) void radon_direct(const float* __restrict__ x,
                                                    float* __restrict__ out) {
    const int a  = blockIdx.x;
    const int hc = blockIdx.y;
    const int w  = threadIdx.x;
    const float ang = (float)a * 0.5f;
    const float t = ang * 0.017453292519943295f;
    const float s = sinf(t);
    const float c = cosf(t);
    const float uw = (float)w - 127.5f;
    const float ax = fmaf(c, uw, 127.5f);
    const float ay = fmaf(s, uw, 127.5f);

    float acc[BB];
#pragma unroll
    for (int b = 0; b < BB; ++b) acc[b] = 0.f;

    const int h0 = hc * 32;
    for (int i = 0; i < 32; ++i) {
        const float uh = (float)(h0 + i) - 127.5f;
        const float ix = fmaf(-s, uh, ax);
        const float iy = fmaf(c, uh, ay);
        const float x0f = floorf(ix), y0f = floorf(iy);
        const float wx1 = ix - x0f, wy1 = iy - y0f;
        const float wx0 = 1.f - wx1, wy0 = 1.f - wy1;
        const int x0 = (int)x0f, y0 = (int)y0f;
        const float vx0 = ((unsigned)x0 < 256u) ? wx0 : 0.f;
        const float vx1 = ((unsigned)(x0 + 1) < 256u) ? wx1 : 0.f;
        const float vy0 = ((unsigned)y0 < 256u) ? wy0 : 0.f;
        const float vy1 = ((unsigned)(y0 + 1) < 256u) ? wy1 : 0.f;
        const int x0c = min(max(x0, 0), 255);
        const int x1c = min(max(x0 + 1, 0), 255);
        const int y0c = min(max(y0, 0), 255);
        const int y1c = min(max(y0 + 1, 0), 255);
        const float w00 = vx0 * vy0, w10 = vx1 * vy0;
        const float w01 = vx0 * vy1, w11 = vx1 * vy1;
        const int l00 = y0c * DD + x0c, l10 = y0c * DD + x1c;
        const int l01 = y1c * DD + x0c, l11 = y1c * DD + x1c;
#pragma unroll
        for (int b = 0; b < BB; ++b) {
            const float* ib = x + (size_t)b * DD * DD;
            acc[b] = fmaf(ib[l00], w00, acc[b]);
            acc[b] = fmaf(ib[l10], w10, acc[b]);
            acc[b] = fmaf(ib[l01], w01, acc[b]);
            acc[b] = fmaf(ib[l11], w11, acc[b]);
        }
    }

    const float sc = 1.0f / 256.0f;
    float* o = out + (size_t)a * DD + w;
#pragma unroll
    for (int b = 0; b < BB; ++b)
        atomicAdd(o + (size_t)b * NA * DD, acc[b] * sc);
}

extern "C" void kernel_launch(void* const* d_in, const int* in_sizes, int n_in,
                              void* d_out, int out_size, void* d_ws, size_t ws_size,
                              hipStream_t stream) {
    const float* x = (const float*)d_in[0];
    float* out = (float*)d_out;

    const size_t need = 2ull * DD * DD * sizeof(uint4);  // 2 MiB
    if (ws_size >= need) {
        uint4* pN = (uint4*)d_ws;
        uint4* pT = pN + (size_t)DD * DD;
        pack_f16<<<256, 256, 0, stream>>>(x, pN, pT);
        radon_pk<<<dim3(NA, 4), 256, 0, stream>>>(pN, pT, out);
    } else {
        (void)hipMemsetAsync(d_out, 0, (size_t)out_size * sizeof(float), stream);
        radon_direct<<<dim3(NA, 8), 256, 0, stream>>>(x, out);
    }
}